// Round 10
// baseline (459.109 us; speedup 1.0000x reference)
//
#include <hip/hip_runtime.h>
#include <math.h>

typedef _Float16 f16;
typedef _Float16 h8  __attribute__((ext_vector_type(8)));
typedef _Float16 h4  __attribute__((ext_vector_type(4)));
typedef _Float16 h2v __attribute__((ext_vector_type(2)));
typedef float    f4  __attribute__((ext_vector_type(4)));

#define N_NODES 100000
#define N_EDGES 1600000
#define N_VOCAB 50000
#define FDIM    128
#define CDIM    20
#define NEG_SLOPE 0.01f

#define NPART 782                    // partitions of 128 dst nodes
#define NB    256                    // histogram/scatter blocks
#define EPB   (N_EDGES / NB)         // 6250 edges per block
#define PBUF  2944                   // repack LDS capacity (mean 2046, +20 sigma)
#define CVT_BLOCKS (N_VOCAB * 32 / 256)      // 6250: emb fp32->fp16 convert

// ---------------------------------------------------------------------------
// K1 (fused): [0,NB) per-block dst-partition histograms (LDS atomics);
// [NB, NB+CVT) sequential emb table convert fp32->fp16 (12.8 MB table —
// layer-0 aggregates straight from it, halving the per-XCD L2 fill vs the
// 25.6 MB materialized x0); last 128 blocks transpose W0/W1.
// ---------------------------------------------------------------------------
__global__ __launch_bounds__(256) void k1_build(const float* __restrict__ emb,
                                                f16* __restrict__ E16,
                                                const int* __restrict__ dst,
                                                int* __restrict__ histG,
                                                const float* __restrict__ W0,
                                                const float* __restrict__ W1,
                                                f16* __restrict__ W0T,
                                                f16* __restrict__ W1T) {
    int b = blockIdx.x, t = threadIdx.x;
    if (b < NB) {
        __shared__ unsigned lh[NPART];
        for (int i = t; i < NPART; i += 256) lh[i] = 0;
        __syncthreads();
        int e0 = b * EPB;
        for (int i = t; i < EPB; i += 256)
            atomicAdd(&lh[dst[e0 + i] >> 7], 1u);
        __syncthreads();
        for (int i = t; i < NPART; i += 256) histG[b * NPART + i] = (int)lh[i];
    } else if (b < NB + CVT_BLOCKS) {
        int gid = (b - NB) * 256 + t;                 // V*32 exact
        float4 vv = ((const float4*)emb)[gid];
        h4 o; o[0] = (f16)vv.x; o[1] = (f16)vv.y; o[2] = (f16)vv.z; o[3] = (f16)vv.w;
        ((h4*)E16)[gid] = o;
    } else {
        int o = (b - NB - CVT_BLOCKS) * 256 + t;      // 32768 total
        const float* W = (o < 16384) ? W0 : W1;
        f16* T = (o < 16384) ? W0T : W1T;
        int o2 = o & 16383;
        int n = o2 >> 7, k = o2 & 127;
        T[o2] = (f16)W[k * 128 + n];
    }
}

// ---------------------------------------------------------------------------
// K2a: one block: column totals + LDS Hillis-Steele scan -> pstart[0..NPART].
// ---------------------------------------------------------------------------
__global__ __launch_bounds__(1024) void k2a_scan(const int* __restrict__ histG,
                                                 int* __restrict__ pstart) {
    __shared__ int a[1024], bb[1024];
    int t = threadIdx.x;
    int s = 0;
    if (t < NPART)
        for (int b = 0; b < NB; ++b) s += histG[b * NPART + t];
    a[t] = s;
    __syncthreads();
    int* cur = a; int* nxt = bb;
    for (int off = 1; off < 1024; off <<= 1) {
        int v = cur[t] + ((t >= off) ? cur[t - off] : 0);
        nxt[t] = v;
        __syncthreads();
        int* tmp = cur; cur = nxt; nxt = tmp;
    }
    if (t < NPART) pstart[t] = cur[t] - s;            // exclusive
    if (t == NPART - 1) pstart[NPART] = cur[t];
}

// ---------------------------------------------------------------------------
// K2b: one wave per partition: scan the 256 per-block counts -> seed offsets.
// ---------------------------------------------------------------------------
__global__ __launch_bounds__(256) void k2b_seed(int* __restrict__ histG,
                                                const int* __restrict__ pstart) {
    int w = blockIdx.x * 4 + (threadIdx.x >> 6);
    if (w >= NPART) return;
    int lane = threadIdx.x & 63;
    int base = pstart[w];
    int v[4], pre[4], s = 0;
    #pragma unroll
    for (int i = 0; i < 4; ++i) v[i] = histG[(lane * 4 + i) * NPART + w];
    #pragma unroll
    for (int i = 0; i < 4; ++i) { pre[i] = s; s += v[i]; }
    int ss = s;
    #pragma unroll
    for (int off = 1; off < 64; off <<= 1) {
        int u = __shfl_up(ss, off);
        if (lane >= off) ss += u;
    }
    int wexcl = ss - s;
    #pragma unroll
    for (int i = 0; i < 4; ++i)
        histG[(lane * 4 + i) * NPART + w] = base + wexcl + pre[i];
}

// ---------------------------------------------------------------------------
// K3: deterministic scatter via LDS cursors seeded from exact offsets.
//   rec = ((dl<<17)|src, ew_f32)
// ---------------------------------------------------------------------------
__global__ __launch_bounds__(256) void k3_scatter(const int* __restrict__ src,
                                                  const int* __restrict__ dst,
                                                  const float* __restrict__ ew,
                                                  const int* __restrict__ histG,
                                                  uint2* __restrict__ recs) {
    __shared__ unsigned cur[NPART];
    int b = blockIdx.x, t = threadIdx.x;
    for (int i = t; i < NPART; i += 256) cur[i] = (unsigned)histG[b * NPART + i];
    __syncthreads();
    int e0 = b * EPB;
    for (int i = t; i < EPB; i += 256) {
        int e = e0 + i;
        int s = src[e], d = dst[e];
        int p = d >> 7, dl = d & 127;
        unsigned pos = atomicAdd(&cur[p], 1u);        // LDS atomic only
        uint2 r; r.x = ((unsigned)dl << 17) | (unsigned)s; r.y = __float_as_uint(ew[e]);
        recs[pos] = r;
    }
}

// ---------------------------------------------------------------------------
// K4: per-partition repack: sort records by dst_local in LDS, emit
// nstart/ncnt, weighted degree -> dinv. Strips dl from rec.x.
// ---------------------------------------------------------------------------
__global__ __launch_bounds__(256) void k4_repack(uint2* __restrict__ recs,
                                                 const int* __restrict__ pstart,
                                                 int* __restrict__ nstart,
                                                 int* __restrict__ ncnt,
                                                 float* __restrict__ dinv) {
    __shared__ uint2    buf[PBUF];                    // 23.5 KB
    __shared__ float    wsum[128];
    __shared__ unsigned hcnt[128], pref[128], cur[128];
    int p = blockIdx.x, t = threadIdx.x;
    if (t < 128) { hcnt[t] = 0; wsum[t] = 0.f; }
    __syncthreads();
    int base = pstart[p];
    int c = pstart[p + 1] - base;
    if (c > PBUF) c = PBUF;
    for (int i = t; i < c; i += 256) {
        uint2 r = recs[base + i];
        buf[i] = r;
        int dl = r.x >> 17;
        atomicAdd(&hcnt[dl], 1u);
        atomicAdd(&wsum[dl], __uint_as_float(r.y));
    }
    __syncthreads();
    if (t == 0) {
        unsigned s = 0;
        for (int k = 0; k < 128; ++k) { pref[k] = s; s += hcnt[k]; }
    }
    __syncthreads();
    if (t < 128) {
        cur[t] = pref[t];
        int g = p * 128 + t;
        if (g < N_NODES) {
            nstart[g] = base + (int)pref[t];
            ncnt[g]   = (int)hcnt[t];
            dinv[g]   = rsqrtf(wsum[t] + 1.0f);
        }
    }
    __syncthreads();
    for (int i = t; i < c; i += 256) {
        uint2 r = buf[i];
        int dl = r.x >> 17;
        unsigned pos = atomicAdd(&cur[dl], 1u);
        uint2 o; o.x = r.x & 0x1FFFFu; o.y = r.y;
        recs[base + pos] = o;
    }
}

// ---------------------------------------------------------------------------
// K5v: layer-0 record: recsV[i] = (ids[src] << 16) | f16bits(dinv[src]*ew)
// (V<2^16 so the vocab row index fits; 4B records halve layer-0 rec traffic
// and remove the per-edge dinv lookup there)
// ---------------------------------------------------------------------------
__global__ __launch_bounds__(256) void k5v(const uint2* __restrict__ recs,
                                           const int* __restrict__ ids,
                                           const float* __restrict__ dinv,
                                           unsigned* __restrict__ recsV) {
    int i = blockIdx.x * 256 + threadIdx.x;
    if (i >= N_EDGES) return;
    uint2 r = recs[i];
    float cf = dinv[r.x] * __uint_as_float(r.y);
    unsigned short hb = __builtin_bit_cast(unsigned short, (f16)cf);
    recsV[i] = ((unsigned)ids[r.x] << 16) | (unsigned)hb;
}

// ---------------------------------------------------------------------------
// aggKV (layer 0): z[n] = dn*(sum coef*E16[vid]) + dn^2*E16[ids[n]].
// Same 8-edge unconditional-load ILP as aggK; 12.8 MB working set (half),
// 4B records, no per-edge dinv.
// ---------------------------------------------------------------------------
__global__ __launch_bounds__(256) void aggKV(const f16* __restrict__ E16,
                                             const int* __restrict__ ids,
                                             const float* __restrict__ dinv,
                                             const int* __restrict__ nstart,
                                             const int* __restrict__ ncnt,
                                             const unsigned* __restrict__ recsV,
                                             f16* __restrict__ Zo) {
    int wave = threadIdx.x >> 6, lane = threadIdx.x & 63;
    int g = lane >> 3, l7 = lane & 7;
    int node = blockIdx.x * 4 + wave;                 // N/4 blocks exact
    int st = nstart[node], c = ncnt[node];
    float acc[16];
    #pragma unroll
    for (int k = 0; k < 16; ++k) acc[k] = 0.f;

    #pragma unroll 2
    for (int j = 0; j < c; j += 8) {
        int jj = j + g;
        int idx = st + (jj < c ? jj : c - 1);         // always valid
        unsigned r = recsV[idx];                      // unconditional
        float cf = (float)__builtin_bit_cast(f16, (unsigned short)(r & 0xFFFFu));
        float cc = (jj < c) ? cf : 0.f;
        const f16* rp = E16 + (size_t)(r >> 16) * 128 + l7 * 16;
        h8 h0 = *(const h8*)rp;                       // unconditional
        h8 h1 = *(const h8*)(rp + 8);
        #pragma unroll
        for (int k = 0; k < 8; ++k) acc[k]     += cc * (float)h0[k];
        #pragma unroll
        for (int k = 0; k < 8; ++k) acc[k + 8] += cc * (float)h1[k];
    }
    #pragma unroll
    for (int k = 0; k < 16; ++k) {
        acc[k] += __shfl_xor(acc[k], 8);
        acc[k] += __shfl_xor(acc[k], 16);
        acc[k] += __shfl_xor(acc[k], 32);
    }
    float dn = dinv[node], d2 = dn * dn;
    int sn = ids[node];
    const f16* sp = E16 + (size_t)sn * 128 + l7 * 16;
    h8 s0 = *(const h8*)sp;
    h8 s1 = *(const h8*)(sp + 8);
    if (g == 0) {
        h8 o0, o1;
        #pragma unroll
        for (int k = 0; k < 8; ++k) o0[k] = (f16)(dn * acc[k]     + d2 * (float)s0[k]);
        #pragma unroll
        for (int k = 0; k < 8; ++k) o1[k] = (f16)(dn * acc[k + 8] + d2 * (float)s1[k]);
        f16* zp = Zo + (size_t)node * 128 + l7 * 16;
        *(h8*)zp = o0;
        *(h8*)(zp + 8) = o1;
    }
}

// ---------------------------------------------------------------------------
// aggK (layers 1): z[n] = dn*(sum dinv[s]*ew*x[s]) + dn^2*x[n].
// 8-edge unconditional clamped loads (R9 pattern).
// ---------------------------------------------------------------------------
__global__ __launch_bounds__(256) void aggK(const f16* __restrict__ Xi,
                                            const float* __restrict__ dinv,
                                            const int* __restrict__ nstart,
                                            const int* __restrict__ ncnt,
                                            const uint2* __restrict__ recs,
                                            f16* __restrict__ Zo) {
    int wave = threadIdx.x >> 6, lane = threadIdx.x & 63;
    int g = lane >> 3, l7 = lane & 7;
    int node = blockIdx.x * 4 + wave;                 // N/4 blocks exact
    int st = nstart[node], c = ncnt[node];
    float acc[16];
    #pragma unroll
    for (int k = 0; k < 16; ++k) acc[k] = 0.f;

    #pragma unroll 2
    for (int j = 0; j < c; j += 8) {
        int jj = j + g;
        int idx = st + (jj < c ? jj : c - 1);         // always valid
        uint2 r = recs[idx];                          // unconditional
        float cf = dinv[r.x] * __uint_as_float(r.y);
        float cc = (jj < c) ? cf : 0.f;
        const f16* rp = Xi + (size_t)r.x * 128 + l7 * 16;
        h8 h0 = *(const h8*)rp;                       // unconditional
        h8 h1 = *(const h8*)(rp + 8);
        #pragma unroll
        for (int k = 0; k < 8; ++k) acc[k]     += cc * (float)h0[k];
        #pragma unroll
        for (int k = 0; k < 8; ++k) acc[k + 8] += cc * (float)h1[k];
    }
    #pragma unroll
    for (int k = 0; k < 16; ++k) {
        acc[k] += __shfl_xor(acc[k], 8);
        acc[k] += __shfl_xor(acc[k], 16);
        acc[k] += __shfl_xor(acc[k], 32);
    }
    float dn = dinv[node], d2 = dn * dn;
    const f16* sp = Xi + (size_t)node * 128 + l7 * 16;
    h8 s0 = *(const h8*)sp;
    h8 s1 = *(const h8*)(sp + 8);
    if (g == 0) {
        h8 o0, o1;
        #pragma unroll
        for (int k = 0; k < 8; ++k) o0[k] = (f16)(dn * acc[k]     + d2 * (float)s0[k]);
        #pragma unroll
        for (int k = 0; k < 8; ++k) o1[k] = (f16)(dn * acc[k + 8] + d2 * (float)s1[k]);
        f16* zp = Zo + (size_t)node * 128 + l7 * 16;
        *(h8*)zp = o0;
        *(h8*)(zp + 8) = o1;
    }
}

// ---------------------------------------------------------------------------
// gemmF: X = leaky(Z @ W + b), fp16 MFMA 16x16x32; 64 rows/block, 4 waves.
// ---------------------------------------------------------------------------
#define GP 136
__global__ __launch_bounds__(256) void gemmF(const f16* __restrict__ Z,
                                             const f16* __restrict__ WT,
                                             const float* __restrict__ bias,
                                             f16* __restrict__ X,
                                             int nrows) {
    __shared__ f16 Xs[64 * GP];
    __shared__ f16 Ws[128 * GP];
    __shared__ float Lb[128];
    int t = threadIdx.x;
    size_t rbase = (size_t)blockIdx.x * 64;

    #pragma unroll
    for (int i = 0; i < 4; ++i) {
        int c = t + 256 * i; int r = c >> 4, c8 = c & 15;
        h8 val = {};
        if (rbase + r < (size_t)nrows)
            val = *(const h8*)(Z + (rbase + r) * 128 + c8 * 8);
        *(h8*)(Xs + r * GP + c8 * 8) = val;
    }
    #pragma unroll
    for (int i = 0; i < 8; ++i) {
        int c = t + 256 * i; int nn = c >> 4, c8 = c & 15;
        *(h8*)(Ws + nn * GP + c8 * 8) = *(const h8*)(WT + nn * 128 + c8 * 8);
    }
    if (t < 128) Lb[t] = bias[t];
    __syncthreads();

    int wave = t >> 6, lane = t & 63, quad = lane >> 4, l15 = lane & 15;
    int m0 = wave * 16;
    f4 acc[8];
    f4 zero = {0.f, 0.f, 0.f, 0.f};
    #pragma unroll
    for (int i = 0; i < 8; ++i) acc[i] = zero;

    #pragma unroll
    for (int kk = 0; kk < 128; kk += 32) {
        h8 a = *(h8*)(Xs + (m0 + l15) * GP + kk + quad * 8);
        #pragma unroll
        for (int nt = 0; nt < 8; ++nt) {
            h8 bf = *(h8*)(Ws + (nt * 16 + l15) * GP + kk + quad * 8);
            acc[nt] = __builtin_amdgcn_mfma_f32_16x16x32_f16(a, bf, acc[nt], 0, 0, 0);
        }
    }
    #pragma unroll
    for (int nt = 0; nt < 8; ++nt) {
        float bb = Lb[nt * 16 + l15];
        #pragma unroll
        for (int r = 0; r < 4; ++r) {
            size_t row = rbase + m0 + quad * 4 + r;
            if (row < (size_t)nrows) {
                float v = acc[nt][r] + bb;
                v = v > 0.f ? v : NEG_SLOPE * v;
                X[row * 128 + nt * 16 + l15] = (f16)v;
            }
        }
    }
}

// ---------------------------------------------------------------------------
// gemm20p: Y = X @ W2 (128 -> 20), fp16 out, padded to stride 32.
// ---------------------------------------------------------------------------
__global__ __launch_bounds__(256) void gemm20p(const f16* __restrict__ X,
                                               const float* __restrict__ W2,
                                               f16* __restrict__ Y) {
    __shared__ f16   Xs[32 * 128];
    __shared__ float Ws[128 * CDIM];
    int t = threadIdx.x;
    const h8* X8 = (const h8*)(X + (size_t)blockIdx.x * 32 * 128);
    ((h8*)Xs)[t]       = X8[t];
    ((h8*)Xs)[t + 256] = X8[t + 256];
    for (int i = t; i < 128 * CDIM; i += 256) Ws[i] = W2[i];
    __syncthreads();
    for (int idx = t; idx < 32 * 32; idx += 256) {
        int r = idx >> 5, cc = idx & 31;
        float acc = 0.f;
        if (cc < CDIM) {
            #pragma unroll 8
            for (int k = 0; k < 128; ++k) acc += (float)Xs[r * 128 + k] * Ws[k * CDIM + cc];
        }
        Y[(size_t)(blockIdx.x * 32 + r) * 32 + cc] = (f16)acc;
    }
}

// ---------------------------------------------------------------------------
// agg20L: out = LSM( b2 + dn*sum(dinv[s]*ew*Y[s]) + dn^2*Y[n] ).  8-edge
// batches with unconditional clamped loads; lane loads h4 of the padded
// 64B row; xor(8,16,32) combine; group-local log-softmax.
// ---------------------------------------------------------------------------
__global__ __launch_bounds__(256) void agg20L(const f16* __restrict__ Y,
                                              const float* __restrict__ dinv,
                                              const int* __restrict__ nstart,
                                              const int* __restrict__ ncnt,
                                              const uint2* __restrict__ recs,
                                              const float* __restrict__ b2,
                                              float* __restrict__ out) {
    int wave = threadIdx.x >> 6, lane = threadIdx.x & 63;
    int g = lane >> 3, l7 = lane & 7;
    int node = blockIdx.x * 4 + wave;
    int st = nstart[node], c = ncnt[node];
    float acc[4];
    #pragma unroll
    for (int k = 0; k < 4; ++k) acc[k] = 0.f;

    #pragma unroll 2
    for (int j = 0; j < c; j += 8) {
        int jj = j + g;
        int idx = st + (jj < c ? jj : c - 1);
        uint2 r = recs[idx];
        float cf = dinv[r.x] * __uint_as_float(r.y);
        float cc = (jj < c) ? cf : 0.f;
        h4 hh = *(const h4*)(Y + (size_t)r.x * 32 + l7 * 4);
        #pragma unroll
        for (int k = 0; k < 4; ++k) acc[k] += cc * (float)hh[k];
    }
    #pragma unroll
    for (int k = 0; k < 4; ++k) {
        acc[k] += __shfl_xor(acc[k], 8);
        acc[k] += __shfl_xor(acc[k], 16);
        acc[k] += __shfl_xor(acc[k], 32);
    }
    float dn = dinv[node], d2 = dn * dn;
    h4 hz = *(const h4*)(Y + (size_t)node * 32 + l7 * 4);
    bool live = (l7 < 5);                             // 5 lanes x 4 = 20 classes
    float tv[4];
    float mx = -INFINITY;
    #pragma unroll
    for (int k = 0; k < 4; ++k) {
        tv[k] = live ? (b2[l7 * 4 + k] + dn * acc[k] + d2 * (float)hz[k]) : -INFINITY;
        mx = fmaxf(mx, tv[k]);
    }
    #pragma unroll
    for (int off = 1; off <= 4; off <<= 1) mx = fmaxf(mx, __shfl_xor(mx, off));
    float ex = 0.f;
    if (live) {
        #pragma unroll
        for (int k = 0; k < 4; ++k) ex += expf(tv[k] - mx);
    }
    #pragma unroll
    for (int off = 1; off <= 4; off <<= 1) ex += __shfl_xor(ex, off);
    float ls = logf(ex);
    if (g == 0 && live) {
        float4 o;
        o.x = tv[0] - mx - ls; o.y = tv[1] - mx - ls;
        o.z = tv[2] - mx - ls; o.w = tv[3] - mx - ls;
        *(float4*)(out + (size_t)node * CDIM + l7 * 4) = o;
    }
}

// ---------------------------------------------------------------------------
extern "C" void kernel_launch(void* const* d_in, const int* in_sizes, int n_in,
                              void* d_out, int out_size, void* d_ws, size_t ws_size,
                              hipStream_t stream) {
    (void)in_sizes; (void)n_in; (void)out_size; (void)ws_size;
    const int*   node_ids = (const int*)d_in[0];
    const int*   e_src    = (const int*)d_in[1];
    const int*   e_dst    = e_src + N_EDGES;
    const float* edge_w   = (const float*)d_in[2];
    const float* emb      = (const float*)d_in[3];
    const float* W0       = (const float*)d_in[4];
    const float* b0       = (const float*)d_in[5];
    const float* W1       = (const float*)d_in[6];
    const float* b1       = (const float*)d_in[7];
    const float* W2       = (const float*)d_in[8];
    const float* b2       = (const float*)d_in[9];
    float* out = (float*)d_out;

    char* w = (char*)d_ws;
    size_t off = 0;
    auto alloc = [&](size_t bytes) {
        void* p = w + off;
        off = (off + bytes + 255) & ~(size_t)255;
        return p;
    };
    f16*      xA     = (f16*)alloc((size_t)N_NODES * FDIM * 2);  // 25.6 MB
    f16*      xB     = (f16*)alloc((size_t)N_NODES * FDIM * 2);  // 25.6 MB
    f16*      ybuf   = xB;                                       // alias (xB free)
    f16*      E16    = (f16*)alloc((size_t)N_VOCAB * FDIM * 2);  // 12.8 MB
    int*      histG  = (int*)alloc((size_t)NB * NPART * 4);      // 800 KB
    int*      pstart = (int*)alloc((size_t)(NPART + 1) * 4);
    int*      nstart = (int*)alloc((size_t)N_NODES * 4);
    int*      ncnt   = (int*)alloc((size_t)N_NODES * 4);
    float*    dinv   = (float*)alloc((size_t)N_NODES * 4);
    f16*      W0T    = (f16*)alloc(16384 * 2);
    f16*      W1T    = (f16*)alloc(16384 * 2);
    uint2*    recs   = (uint2*)alloc((size_t)N_EDGES * 8);       // 12.8 MB
    unsigned* recsV  = (unsigned*)alloc((size_t)N_EDGES * 4);    // 6.4 MB

    k1_build<<<NB + CVT_BLOCKS + 128, 256, 0, stream>>>(
        emb, E16, e_dst, histG, W0, W1, W0T, W1T);
    k2a_scan<<<1, 1024, 0, stream>>>(histG, pstart);
    k2b_seed<<<(NPART + 3) / 4, 256, 0, stream>>>(histG, pstart);
    k3_scatter<<<NB, 256, 0, stream>>>(e_src, e_dst, edge_w, histG, recs);
    k4_repack<<<NPART, 256, 0, stream>>>(recs, pstart, nstart, ncnt, dinv);
    k5v<<<(N_EDGES + 255) / 256, 256, 0, stream>>>(recs, node_ids, dinv, recsV);

    int gblocks = (N_NODES + 63) / 64;
    // layer 0:  z = A.emb16[ids]  (12.8 MB working set) ; x1 = leaky(z W0 + b0)
    aggKV<<<N_NODES / 4, 256, 0, stream>>>(E16, node_ids, dinv, nstart, ncnt, recsV, xB);
    gemmF<<<gblocks, 256, 0, stream>>>(xB, W0T, b0, xA, N_NODES);
    // layer 1
    aggK <<<N_NODES / 4, 256, 0, stream>>>(xA, dinv, nstart, ncnt, recs, xB);
    gemmF<<<gblocks, 256, 0, stream>>>(xB, W1T, b1, xA, N_NODES);
    // layer 2:  y = x2 W2 (padded) ; out = LSM(A.y + b2)
    gemm20p<<<N_NODES / 32, 256, 0, stream>>>(xA, W2, ybuf);
    agg20L <<<N_NODES / 4, 256, 0, stream>>>(ybuf, dinv, nstart, ncnt, recs, b2, out);
}

// Round 11
// 446.472 us; speedup vs baseline: 1.0283x; 1.0283x over previous
//
#include <hip/hip_runtime.h>
#include <math.h>

typedef _Float16 f16;
typedef _Float16 h8  __attribute__((ext_vector_type(8)));
typedef _Float16 h4  __attribute__((ext_vector_type(4)));
typedef float    f4  __attribute__((ext_vector_type(4)));

#define N_NODES 100000
#define N_EDGES 1600000
#define FDIM    128
#define CDIM    20
#define NEG_SLOPE 0.01f

#define NPART 782                    // partitions of 128 dst nodes
#define NB    256                    // histogram/scatter blocks
#define EPB   (N_EDGES / NB)         // 6250 edges per block
#define PBUF  2944                   // repack LDS capacity (mean 2046, +20 sigma)
#define GATHER_BLOCKS (N_NODES * 32 / 256)   // 12500
#define GP    136                    // LDS pitch in halves

// ---------------------------------------------------------------------------
// K1 (fused): [0,NB) per-block dst-partition histograms (LDS atomics);
// [NB, NB+GATHER) emb-row gather fp32->fp16 into xA; last 128 blocks
// transpose W0/W1 to fp16 [n][k].
// ---------------------------------------------------------------------------
__global__ __launch_bounds__(256) void k1_build(const int* __restrict__ ids,
                                                const float* __restrict__ emb,
                                                f16* __restrict__ X,
                                                const int* __restrict__ dst,
                                                int* __restrict__ histG,
                                                const float* __restrict__ W0,
                                                const float* __restrict__ W1,
                                                f16* __restrict__ W0T,
                                                f16* __restrict__ W1T) {
    int b = blockIdx.x, t = threadIdx.x;
    if (b < NB) {
        __shared__ unsigned lh[NPART];
        for (int i = t; i < NPART; i += 256) lh[i] = 0;
        __syncthreads();
        int e0 = b * EPB;
        for (int i = t; i < EPB; i += 256)
            atomicAdd(&lh[dst[e0 + i] >> 7], 1u);
        __syncthreads();
        for (int i = t; i < NPART; i += 256) histG[b * NPART + i] = (int)lh[i];
    } else if (b < NB + GATHER_BLOCKS) {
        int gid = (b - NB) * 256 + t;                 // N*32 exact
        int n = gid >> 5, qq = gid & 31;
        int v = ids[n];
        float4 vv = ((const float4*)emb)[(size_t)v * 32 + qq];
        h4 o; o[0] = (f16)vv.x; o[1] = (f16)vv.y; o[2] = (f16)vv.z; o[3] = (f16)vv.w;
        ((h4*)X)[(size_t)n * 32 + qq] = o;
    } else {
        int o = (b - NB - GATHER_BLOCKS) * 256 + t;   // 32768 total
        const float* W = (o < 16384) ? W0 : W1;
        f16* T = (o < 16384) ? W0T : W1T;
        int o2 = o & 16383;
        int n = o2 >> 7, k = o2 & 127;
        T[o2] = (f16)W[k * 128 + n];
    }
}

// ---------------------------------------------------------------------------
// K2a: one block: column totals + LDS Hillis-Steele scan -> pstart[0..NPART].
// ---------------------------------------------------------------------------
__global__ __launch_bounds__(1024) void k2a_scan(const int* __restrict__ histG,
                                                 int* __restrict__ pstart) {
    __shared__ int a[1024], bb[1024];
    int t = threadIdx.x;
    int s = 0;
    if (t < NPART)
        for (int b = 0; b < NB; ++b) s += histG[b * NPART + t];
    a[t] = s;
    __syncthreads();
    int* cur = a; int* nxt = bb;
    for (int off = 1; off < 1024; off <<= 1) {
        int v = cur[t] + ((t >= off) ? cur[t - off] : 0);
        nxt[t] = v;
        __syncthreads();
        int* tmp = cur; cur = nxt; nxt = tmp;
    }
    if (t < NPART) pstart[t] = cur[t] - s;            // exclusive
    if (t == NPART - 1) pstart[NPART] = cur[t];
}

// ---------------------------------------------------------------------------
// K2b: one wave per partition: scan the 256 per-block counts -> seed offsets.
// ---------------------------------------------------------------------------
__global__ __launch_bounds__(256) void k2b_seed(int* __restrict__ histG,
                                                const int* __restrict__ pstart) {
    int w = blockIdx.x * 4 + (threadIdx.x >> 6);
    if (w >= NPART) return;
    int lane = threadIdx.x & 63;
    int base = pstart[w];
    int v[4], pre[4], s = 0;
    #pragma unroll
    for (int i = 0; i < 4; ++i) v[i] = histG[(lane * 4 + i) * NPART + w];
    #pragma unroll
    for (int i = 0; i < 4; ++i) { pre[i] = s; s += v[i]; }
    int ss = s;
    #pragma unroll
    for (int off = 1; off < 64; off <<= 1) {
        int u = __shfl_up(ss, off);
        if (lane >= off) ss += u;
    }
    int wexcl = ss - s;
    #pragma unroll
    for (int i = 0; i < 4; ++i)
        histG[(lane * 4 + i) * NPART + w] = base + wexcl + pre[i];
}

// ---------------------------------------------------------------------------
// K3: deterministic scatter via LDS cursors seeded from exact offsets.
//   rec = ((dl<<17)|src, ew_f32)
// ---------------------------------------------------------------------------
__global__ __launch_bounds__(256) void k3_scatter(const int* __restrict__ src,
                                                  const int* __restrict__ dst,
                                                  const float* __restrict__ ew,
                                                  const int* __restrict__ histG,
                                                  uint2* __restrict__ recs) {
    __shared__ unsigned cur[NPART];
    int b = blockIdx.x, t = threadIdx.x;
    for (int i = t; i < NPART; i += 256) cur[i] = (unsigned)histG[b * NPART + i];
    __syncthreads();
    int e0 = b * EPB;
    for (int i = t; i < EPB; i += 256) {
        int e = e0 + i;
        int s = src[e], d = dst[e];
        int p = d >> 7, dl = d & 127;
        unsigned pos = atomicAdd(&cur[p], 1u);        // LDS atomic only
        uint2 r; r.x = ((unsigned)dl << 17) | (unsigned)s; r.y = __float_as_uint(ew[e]);
        recs[pos] = r;
    }
}

// ---------------------------------------------------------------------------
// K4: per-partition repack: sort records by dst_local in LDS, emit
// nstart/ncnt, weighted degree -> dinv. Strips dl from rec.x.
// ---------------------------------------------------------------------------
__global__ __launch_bounds__(256) void k4_repack(uint2* __restrict__ recs,
                                                 const int* __restrict__ pstart,
                                                 int* __restrict__ nstart,
                                                 int* __restrict__ ncnt,
                                                 float* __restrict__ dinv) {
    __shared__ uint2    buf[PBUF];                    // 23.5 KB
    __shared__ float    wsum[128];
    __shared__ unsigned hcnt[128], pref[128], cur[128];
    int p = blockIdx.x, t = threadIdx.x;
    if (t < 128) { hcnt[t] = 0; wsum[t] = 0.f; }
    __syncthreads();
    int base = pstart[p];
    int c = pstart[p + 1] - base;
    if (c > PBUF) c = PBUF;
    for (int i = t; i < c; i += 256) {
        uint2 r = recs[base + i];
        buf[i] = r;
        int dl = r.x >> 17;
        atomicAdd(&hcnt[dl], 1u);
        atomicAdd(&wsum[dl], __uint_as_float(r.y));
    }
    __syncthreads();
    if (t == 0) {
        unsigned s = 0;
        for (int k = 0; k < 128; ++k) { pref[k] = s; s += hcnt[k]; }
    }
    __syncthreads();
    if (t < 128) {
        cur[t] = pref[t];
        int g = p * 128 + t;
        if (g < N_NODES) {
            nstart[g] = base + (int)pref[t];
            ncnt[g]   = (int)hcnt[t];
            dinv[g]   = rsqrtf(wsum[t] + 1.0f);
        }
    }
    __syncthreads();
    for (int i = t; i < c; i += 256) {
        uint2 r = buf[i];
        int dl = r.x >> 17;
        unsigned pos = atomicAdd(&cur[dl], 1u);
        uint2 o; o.x = r.x & 0x1FFFFu; o.y = r.y;
        recs[base + pos] = o;
    }
}

// ---------------------------------------------------------------------------
// Shared device helper: aggregate 8 nodes per wave into the LDS z-tile.
// Wave = 64 lanes; group g of 8 lanes handles edge st+j+g, lane loads 32B of
// the source row; unconditional clamped loads (R9 ILP pattern); xor-combine.
// ---------------------------------------------------------------------------
__device__ __forceinline__ void agg_to_lds(const f16* __restrict__ Xi,
                                           const float* __restrict__ dinv,
                                           const int* __restrict__ nstart,
                                           const int* __restrict__ ncnt,
                                           const uint2* __restrict__ recs,
                                           f16* __restrict__ Xs,
                                           int wave, int lane, int nb) {
    int g = lane >> 3, l7 = lane & 7;
    for (int nn = 0; nn < 8; ++nn) {
        int node = nb + nn;
        if (node < N_NODES) {
            int st = nstart[node], c = ncnt[node];
            float acc[16];
            #pragma unroll
            for (int k = 0; k < 16; ++k) acc[k] = 0.f;
            for (int j = 0; j < c; j += 8) {
                int jj = j + g;
                int idx = st + (jj < c ? jj : c - 1);     // always valid
                uint2 r = recs[idx];                      // unconditional
                float cf = dinv[r.x] * __uint_as_float(r.y);
                float cc = (jj < c) ? cf : 0.f;
                const f16* rp = Xi + (size_t)r.x * 128 + l7 * 16;
                h8 h0 = *(const h8*)rp;
                h8 h1 = *(const h8*)(rp + 8);
                #pragma unroll
                for (int k = 0; k < 8; ++k) acc[k]     += cc * (float)h0[k];
                #pragma unroll
                for (int k = 0; k < 8; ++k) acc[k + 8] += cc * (float)h1[k];
            }
            #pragma unroll
            for (int k = 0; k < 16; ++k) {
                acc[k] += __shfl_xor(acc[k], 8);
                acc[k] += __shfl_xor(acc[k], 16);
                acc[k] += __shfl_xor(acc[k], 32);
            }
            if (g == 0) {
                float dn = dinv[node], d2 = dn * dn;
                const f16* sp = Xi + (size_t)node * 128 + l7 * 16;
                h8 s0 = *(const h8*)sp;
                h8 s1 = *(const h8*)(sp + 8);
                h8 o0, o1;
                #pragma unroll
                for (int k = 0; k < 8; ++k) o0[k] = (f16)(dn * acc[k]     + d2 * (float)s0[k]);
                #pragma unroll
                for (int k = 0; k < 8; ++k) o1[k] = (f16)(dn * acc[k + 8] + d2 * (float)s1[k]);
                f16* zp = Xs + (wave * 8 + nn) * GP + l7 * 16;
                *(h8*)zp = o0;
                *(h8*)(zp + 8) = o1;
            }
        } else if (g == 0) {
            h8 z = {};
            f16* zp = Xs + (wave * 8 + nn) * GP + l7 * 16;
            *(h8*)zp = z;
            *(h8*)(zp + 8) = z;
        }
    }
}

// ---------------------------------------------------------------------------
// fusedL0: block of 64 nodes (512 thr, 8 waves). Agg xA -> LDS z; barrier;
// 64x128 @ 128x128 MFMA from LDS; leaky(+b) -> xB. Agg (VMEM pipe) of one
// block overlaps GEMM (MFMA pipe) of another on the same CU.
// ---------------------------------------------------------------------------
__global__ __launch_bounds__(512) void fusedL0(const f16* __restrict__ Xi,
                                               const float* __restrict__ dinv,
                                               const int* __restrict__ nstart,
                                               const int* __restrict__ ncnt,
                                               const uint2* __restrict__ recs,
                                               const f16* __restrict__ WT,
                                               const float* __restrict__ bias,
                                               f16* __restrict__ Xo) {
    __shared__ f16   Xs[64 * GP];    // 17.0 KB  (z tile)
    __shared__ f16   Ws[128 * GP];   // 34.0 KB  (W, [n][k])
    __shared__ float Lb[128];
    int t = threadIdx.x;
    #pragma unroll
    for (int i = 0; i < 4; ++i) {                    // 2048 h8 chunks
        int c = t + 512 * i; int nn = c >> 4, c8 = c & 15;
        *(h8*)(Ws + nn * GP + c8 * 8) = *(const h8*)(WT + nn * 128 + c8 * 8);
    }
    if (t < 128) Lb[t] = bias[t];

    int wave = t >> 6, lane = t & 63;
    agg_to_lds(Xi, dinv, nstart, ncnt, recs, Xs, wave, lane,
               blockIdx.x * 64 + wave * 8);
    __syncthreads();

    int quad = lane >> 4, l15 = lane & 15;
    int mtile = wave & 3, nh = wave >> 2;            // 4 m-tiles x 2 n-halves
    f4 a4[4]; f4 zero = {0.f, 0.f, 0.f, 0.f};
    #pragma unroll
    for (int i = 0; i < 4; ++i) a4[i] = zero;
    #pragma unroll
    for (int kk = 0; kk < 128; kk += 32) {
        h8 a = *(h8*)(Xs + (mtile * 16 + l15) * GP + kk + quad * 8);
        #pragma unroll
        for (int nt4 = 0; nt4 < 4; ++nt4) {
            int nt = nh * 4 + nt4;
            h8 b = *(h8*)(Ws + (nt * 16 + l15) * GP + kk + quad * 8);
            a4[nt4] = __builtin_amdgcn_mfma_f32_16x16x32_f16(a, b, a4[nt4], 0, 0, 0);
        }
    }
    size_t rbase = (size_t)blockIdx.x * 64;
    #pragma unroll
    for (int nt4 = 0; nt4 < 4; ++nt4) {
        int col = (nh * 4 + nt4) * 16 + l15;
        float bb = Lb[col];
        #pragma unroll
        for (int r = 0; r < 4; ++r) {
            size_t row = rbase + mtile * 16 + quad * 4 + r;
            if (row < N_NODES) {
                float v = a4[nt4][r] + bb;
                v = v > 0.f ? v : NEG_SLOPE * v;
                Xo[row * 128 + col] = (f16)v;
            }
        }
    }
}

// ---------------------------------------------------------------------------
// fusedL1: as fusedL0, plus the 128->20 GEMM fused into the epilogue:
// x2 frags -> LDS (reusing z tile), W2 (zero-padded to 32 cols) -> LDS
// (reusing W region), 4 more MFMAs/wave -> y (stride-32 fp16, 6.4 MB).
// x2 never touches HBM.
// ---------------------------------------------------------------------------
__global__ __launch_bounds__(512) void fusedL1(const f16* __restrict__ Xi,
                                               const float* __restrict__ dinv,
                                               const int* __restrict__ nstart,
                                               const int* __restrict__ ncnt,
                                               const uint2* __restrict__ recs,
                                               const f16* __restrict__ WT,
                                               const float* __restrict__ bias,
                                               const float* __restrict__ W2,
                                               f16* __restrict__ Y) {
    __shared__ f16   Xs[64 * GP];
    __shared__ f16   Ws[128 * GP];
    __shared__ float Lb[128];
    int t = threadIdx.x;
    #pragma unroll
    for (int i = 0; i < 4; ++i) {
        int c = t + 512 * i; int nn = c >> 4, c8 = c & 15;
        *(h8*)(Ws + nn * GP + c8 * 8) = *(const h8*)(WT + nn * 128 + c8 * 8);
    }
    if (t < 128) Lb[t] = bias[t];

    int wave = t >> 6, lane = t & 63;
    agg_to_lds(Xi, dinv, nstart, ncnt, recs, Xs, wave, lane,
               blockIdx.x * 64 + wave * 8);
    __syncthreads();

    int quad = lane >> 4, l15 = lane & 15;
    int mtile = wave & 3, nh = wave >> 2;
    f4 a4[4]; f4 zero = {0.f, 0.f, 0.f, 0.f};
    #pragma unroll
    for (int i = 0; i < 4; ++i) a4[i] = zero;
    #pragma unroll
    for (int kk = 0; kk < 128; kk += 32) {
        h8 a = *(h8*)(Xs + (mtile * 16 + l15) * GP + kk + quad * 8);
        #pragma unroll
        for (int nt4 = 0; nt4 < 4; ++nt4) {
            int nt = nh * 4 + nt4;
            h8 b = *(h8*)(Ws + (nt * 16 + l15) * GP + kk + quad * 8);
            a4[nt4] = __builtin_amdgcn_mfma_f32_16x16x32_f16(a, b, a4[nt4], 0, 0, 0);
        }
    }
    __syncthreads();                                 // all z/W reads done
    // x2 = leaky(acc + b) -> LDS (overwrites z tile)
    #pragma unroll
    for (int nt4 = 0; nt4 < 4; ++nt4) {
        int col = (nh * 4 + nt4) * 16 + l15;
        float bb = Lb[col];
        #pragma unroll
        for (int r = 0; r < 4; ++r) {
            float v = a4[nt4][r] + bb;
            v = v > 0.f ? v : NEG_SLOPE * v;
            Xs[(mtile * 16 + quad * 4 + r) * GP + col] = (f16)v;
        }
    }
    // stage W2 as B-frags [col][k], cols 20..31 zero (overwrites W region)
    for (int i = t; i < 32 * 128; i += 512) {
        int cc = i >> 7, k = i & 127;
        Ws[cc * GP + k] = (cc < CDIM) ? (f16)W2[k * CDIM + cc] : (f16)0.f;
    }
    __syncthreads();
    int ntile = wave >> 2;                           // 2 n-tiles of 16 cols
    f4 ya = zero;
    #pragma unroll
    for (int kk = 0; kk < 128; kk += 32) {
        h8 a = *(h8*)(Xs + (mtile * 16 + l15) * GP + kk + quad * 8);
        h8 b = *(h8*)(Ws + (ntile * 16 + l15) * GP + kk + quad * 8);
        ya = __builtin_amdgcn_mfma_f32_16x16x32_f16(a, b, ya, 0, 0, 0);
    }
    size_t rbase = (size_t)blockIdx.x * 64;
    #pragma unroll
    for (int r = 0; r < 4; ++r) {
        size_t row = rbase + mtile * 16 + quad * 4 + r;
        if (row < N_NODES)
            Y[row * 32 + ntile * 16 + l15] = (f16)ya[r];
    }
}

// ---------------------------------------------------------------------------
// agg20L: out = LSM( b2 + dn*sum(dinv[s]*ew*Y[s]) + dn^2*Y[n] ).  8-edge
// batches with unconditional clamped loads; lane loads h4 of the padded
// 64B row; xor(8,16,32) combine; group-local log-softmax.
// ---------------------------------------------------------------------------
__global__ __launch_bounds__(256) void agg20L(const f16* __restrict__ Y,
                                              const float* __restrict__ dinv,
                                              const int* __restrict__ nstart,
                                              const int* __restrict__ ncnt,
                                              const uint2* __restrict__ recs,
                                              const float* __restrict__ b2,
                                              float* __restrict__ out) {
    int wave = threadIdx.x >> 6, lane = threadIdx.x & 63;
    int g = lane >> 3, l7 = lane & 7;
    int node = blockIdx.x * 4 + wave;
    int st = nstart[node], c = ncnt[node];
    float acc[4];
    #pragma unroll
    for (int k = 0; k < 4; ++k) acc[k] = 0.f;

    #pragma unroll 2
    for (int j = 0; j < c; j += 8) {
        int jj = j + g;
        int idx = st + (jj < c ? jj : c - 1);
        uint2 r = recs[idx];
        float cf = dinv[r.x] * __uint_as_float(r.y);
        float cc = (jj < c) ? cf : 0.f;
        h4 hh = *(const h4*)(Y + (size_t)r.x * 32 + l7 * 4);
        #pragma unroll
        for (int k = 0; k < 4; ++k) acc[k] += cc * (float)hh[k];
    }
    #pragma unroll
    for (int k = 0; k < 4; ++k) {
        acc[k] += __shfl_xor(acc[k], 8);
        acc[k] += __shfl_xor(acc[k], 16);
        acc[k] += __shfl_xor(acc[k], 32);
    }
    float dn = dinv[node], d2 = dn * dn;
    h4 hz = *(const h4*)(Y + (size_t)node * 32 + l7 * 4);
    bool live = (l7 < 5);                             // 5 lanes x 4 = 20 classes
    float tv[4];
    float mx = -INFINITY;
    #pragma unroll
    for (int k = 0; k < 4; ++k) {
        tv[k] = live ? (b2[l7 * 4 + k] + dn * acc[k] + d2 * (float)hz[k]) : -INFINITY;
        mx = fmaxf(mx, tv[k]);
    }
    #pragma unroll
    for (int off = 1; off <= 4; off <<= 1) mx = fmaxf(mx, __shfl_xor(mx, off));
    float ex = 0.f;
    if (live) {
        #pragma unroll
        for (int k = 0; k < 4; ++k) ex += expf(tv[k] - mx);
    }
    #pragma unroll
    for (int off = 1; off <= 4; off <<= 1) ex += __shfl_xor(ex, off);
    float ls = logf(ex);
    if (g == 0 && live) {
        float4 o;
        o.x = tv[0] - mx - ls; o.y = tv[1] - mx - ls;
        o.z = tv[2] - mx - ls; o.w = tv[3] - mx - ls;
        *(float4*)(out + (size_t)node * CDIM + l7 * 4) = o;
    }
}

// ---------------------------------------------------------------------------
extern "C" void kernel_launch(void* const* d_in, const int* in_sizes, int n_in,
                              void* d_out, int out_size, void* d_ws, size_t ws_size,
                              hipStream_t stream) {
    (void)in_sizes; (void)n_in; (void)out_size; (void)ws_size;
    const int*   node_ids = (const int*)d_in[0];
    const int*   e_src    = (const int*)d_in[1];
    const int*   e_dst    = e_src + N_EDGES;
    const float* edge_w   = (const float*)d_in[2];
    const float* emb      = (const float*)d_in[3];
    const float* W0       = (const float*)d_in[4];
    const float* b0       = (const float*)d_in[5];
    const float* W1       = (const float*)d_in[6];
    const float* b1       = (const float*)d_in[7];
    const float* W2       = (const float*)d_in[8];
    const float* b2       = (const float*)d_in[9];
    float* out = (float*)d_out;

    char* w = (char*)d_ws;
    size_t off = 0;
    auto alloc = [&](size_t bytes) {
        void* p = w + off;
        off = (off + bytes + 255) & ~(size_t)255;
        return p;
    };
    f16*   xA     = (f16*)alloc((size_t)N_NODES * FDIM * 2);     // 25.6 MB
    f16*   xB     = (f16*)alloc((size_t)N_NODES * FDIM * 2);     // 25.6 MB
    f16*   ybuf   = (f16*)alloc((size_t)N_NODES * 32 * 2);       // 6.4 MB
    int*   histG  = (int*)alloc((size_t)NB * NPART * 4);         // 800 KB
    int*   pstart = (int*)alloc((size_t)(NPART + 1) * 4);
    int*   nstart = (int*)alloc((size_t)N_NODES * 4);
    int*   ncnt   = (int*)alloc((size_t)N_NODES * 4);
    float* dinv   = (float*)alloc((size_t)N_NODES * 4);
    f16*   W0T    = (f16*)alloc(16384 * 2);
    f16*   W1T    = (f16*)alloc(16384 * 2);
    uint2* recs   = (uint2*)alloc((size_t)N_EDGES * 8);          // 12.8 MB

    k1_build<<<NB + GATHER_BLOCKS + 128, 256, 0, stream>>>(
        node_ids, emb, xA, e_dst, histG, W0, W1, W0T, W1T);
    k2a_scan<<<1, 1024, 0, stream>>>(histG, pstart);
    k2b_seed<<<(NPART + 3) / 4, 256, 0, stream>>>(histG, pstart);
    k3_scatter<<<NB, 256, 0, stream>>>(e_src, e_dst, edge_w, histG, recs);
    k4_repack<<<NPART, 256, 0, stream>>>(recs, pstart, nstart, ncnt, dinv);

    int fblocks = (N_NODES + 63) / 64;               // 1563
    // layer 0:  x1 = leaky((A.x0) W0 + b0)          (agg+GEMM fused)
    fusedL0<<<fblocks, 512, 0, stream>>>(xA, dinv, nstart, ncnt, recs, W0T, b0, xB);
    // layer 1 + 128->20:  y = leaky((A.x1) W1 + b1) W2   (x2 never hits HBM)
    fusedL1<<<fblocks, 512, 0, stream>>>(xB, dinv, nstart, ncnt, recs, W1T, b1, W2, ybuf);
    // out = LSM(b2 + A.y)
    agg20L<<<N_NODES / 4, 256, 0, stream>>>(ybuf, dinv, nstart, ncnt, recs, b2, out);
}

// Round 12
// 437.590 us; speedup vs baseline: 1.0492x; 1.0203x over previous
//
#include <hip/hip_runtime.h>
#include <math.h>

typedef _Float16 f16;
typedef _Float16 h8  __attribute__((ext_vector_type(8)));
typedef _Float16 h4  __attribute__((ext_vector_type(4)));
typedef float    f4  __attribute__((ext_vector_type(4)));

#define N_NODES 100000
#define N_EDGES 1600000
#define FDIM    128
#define CDIM    20
#define NEG_SLOPE 0.01f

#define NPART 782                    // partitions of 128 dst nodes
#define NB    256                    // histogram/scatter blocks
#define EPB   (N_EDGES / NB)         // 6250 edges per block
#define PBUF  2944                   // repack LDS capacity (mean 2046, +20 sigma)
#define GATHER_BLOCKS (N_NODES * 32 / 256)   // 12500
#define GP    136                    // LDS pitch in halves

// ---------------------------------------------------------------------------
// K1 (fused): [0,NB) per-block dst-partition histograms (LDS atomics);
// [NB, NB+GATHER) emb-row gather fp32->fp16 into xA; then 128 blocks
// transpose W0/W1 to fp16 [n][k]; last 16 blocks build W2T (32x128,
// zero-padded cols 20..31).
// ---------------------------------------------------------------------------
__global__ __launch_bounds__(256) void k1_build(const int* __restrict__ ids,
                                                const float* __restrict__ emb,
                                                f16* __restrict__ X,
                                                const int* __restrict__ dst,
                                                int* __restrict__ histG,
                                                const float* __restrict__ W0,
                                                const float* __restrict__ W1,
                                                const float* __restrict__ W2,
                                                f16* __restrict__ W0T,
                                                f16* __restrict__ W1T,
                                                f16* __restrict__ W2T) {
    int b = blockIdx.x, t = threadIdx.x;
    if (b < NB) {
        __shared__ unsigned lh[NPART];
        for (int i = t; i < NPART; i += 256) lh[i] = 0;
        __syncthreads();
        int e0 = b * EPB;
        for (int i = t; i < EPB; i += 256)
            atomicAdd(&lh[dst[e0 + i] >> 7], 1u);
        __syncthreads();
        for (int i = t; i < NPART; i += 256) histG[b * NPART + i] = (int)lh[i];
    } else if (b < NB + GATHER_BLOCKS) {
        int gid = (b - NB) * 256 + t;                 // N*32 exact
        int n = gid >> 5, qq = gid & 31;
        int v = ids[n];
        float4 vv = ((const float4*)emb)[(size_t)v * 32 + qq];
        h4 o; o[0] = (f16)vv.x; o[1] = (f16)vv.y; o[2] = (f16)vv.z; o[3] = (f16)vv.w;
        ((h4*)X)[(size_t)n * 32 + qq] = o;
    } else if (b < NB + GATHER_BLOCKS + 128) {
        int o = (b - NB - GATHER_BLOCKS) * 256 + t;   // 32768 total
        const float* W = (o < 16384) ? W0 : W1;
        f16* T = (o < 16384) ? W0T : W1T;
        int o2 = o & 16383;
        int n = o2 >> 7, k = o2 & 127;
        T[o2] = (f16)W[k * 128 + n];
    } else {
        int o = (b - NB - GATHER_BLOCKS - 128) * 256 + t;   // 4096 total
        int cc = o >> 7, k = o & 127;
        W2T[o] = (cc < CDIM) ? (f16)W2[k * CDIM + cc] : (f16)0.f;
    }
}

// ---------------------------------------------------------------------------
// K2a: one block: column totals + LDS Hillis-Steele scan -> pstart[0..NPART].
// ---------------------------------------------------------------------------
__global__ __launch_bounds__(1024) void k2a_scan(const int* __restrict__ histG,
                                                 int* __restrict__ pstart) {
    __shared__ int a[1024], bb[1024];
    int t = threadIdx.x;
    int s = 0;
    if (t < NPART)
        for (int b = 0; b < NB; ++b) s += histG[b * NPART + t];
    a[t] = s;
    __syncthreads();
    int* cur = a; int* nxt = bb;
    for (int off = 1; off < 1024; off <<= 1) {
        int v = cur[t] + ((t >= off) ? cur[t - off] : 0);
        nxt[t] = v;
        __syncthreads();
        int* tmp = cur; cur = nxt; nxt = tmp;
    }
    if (t < NPART) pstart[t] = cur[t] - s;            // exclusive
    if (t == NPART - 1) pstart[NPART] = cur[t];
}

// ---------------------------------------------------------------------------
// K2b: one wave per partition: scan the 256 per-block counts -> seed offsets.
// ---------------------------------------------------------------------------
__global__ __launch_bounds__(256) void k2b_seed(int* __restrict__ histG,
                                                const int* __restrict__ pstart) {
    int w = blockIdx.x * 4 + (threadIdx.x >> 6);
    if (w >= NPART) return;
    int lane = threadIdx.x & 63;
    int base = pstart[w];
    int v[4], pre[4], s = 0;
    #pragma unroll
    for (int i = 0; i < 4; ++i) v[i] = histG[(lane * 4 + i) * NPART + w];
    #pragma unroll
    for (int i = 0; i < 4; ++i) { pre[i] = s; s += v[i]; }
    int ss = s;
    #pragma unroll
    for (int off = 1; off < 64; off <<= 1) {
        int u = __shfl_up(ss, off);
        if (lane >= off) ss += u;
    }
    int wexcl = ss - s;
    #pragma unroll
    for (int i = 0; i < 4; ++i)
        histG[(lane * 4 + i) * NPART + w] = base + wexcl + pre[i];
}

// ---------------------------------------------------------------------------
// K3: deterministic scatter via LDS cursors seeded from exact offsets.
//   rec = ((dl<<17)|src, ew_f32)
// ---------------------------------------------------------------------------
__global__ __launch_bounds__(256) void k3_scatter(const int* __restrict__ src,
                                                  const int* __restrict__ dst,
                                                  const float* __restrict__ ew,
                                                  const int* __restrict__ histG,
                                                  uint2* __restrict__ recs) {
    __shared__ unsigned cur[NPART];
    int b = blockIdx.x, t = threadIdx.x;
    for (int i = t; i < NPART; i += 256) cur[i] = (unsigned)histG[b * NPART + i];
    __syncthreads();
    int e0 = b * EPB;
    for (int i = t; i < EPB; i += 256) {
        int e = e0 + i;
        int s = src[e], d = dst[e];
        int p = d >> 7, dl = d & 127;
        unsigned pos = atomicAdd(&cur[p], 1u);        // LDS atomic only
        uint2 r; r.x = ((unsigned)dl << 17) | (unsigned)s; r.y = __float_as_uint(ew[e]);
        recs[pos] = r;
    }
}

// ---------------------------------------------------------------------------
// K4: per-partition repack: sort records by dst_local in LDS, emit
// nstart/ncnt, weighted degree -> dinv. Strips dl from rec.x.
// ---------------------------------------------------------------------------
__global__ __launch_bounds__(256) void k4_repack(uint2* __restrict__ recs,
                                                 const int* __restrict__ pstart,
                                                 int* __restrict__ nstart,
                                                 int* __restrict__ ncnt,
                                                 float* __restrict__ dinv) {
    __shared__ uint2    buf[PBUF];                    // 23.5 KB
    __shared__ float    wsum[128];
    __shared__ unsigned hcnt[128], pref[128], cur[128];
    int p = blockIdx.x, t = threadIdx.x;
    if (t < 128) { hcnt[t] = 0; wsum[t] = 0.f; }
    __syncthreads();
    int base = pstart[p];
    int c = pstart[p + 1] - base;
    if (c > PBUF) c = PBUF;
    for (int i = t; i < c; i += 256) {
        uint2 r = recs[base + i];
        buf[i] = r;
        int dl = r.x >> 17;
        atomicAdd(&hcnt[dl], 1u);
        atomicAdd(&wsum[dl], __uint_as_float(r.y));
    }
    __syncthreads();
    if (t == 0) {
        unsigned s = 0;
        for (int k = 0; k < 128; ++k) { pref[k] = s; s += hcnt[k]; }
    }
    __syncthreads();
    if (t < 128) {
        cur[t] = pref[t];
        int g = p * 128 + t;
        if (g < N_NODES) {
            nstart[g] = base + (int)pref[t];
            ncnt[g]   = (int)hcnt[t];
            dinv[g]   = rsqrtf(wsum[t] + 1.0f);
        }
    }
    __syncthreads();
    for (int i = t; i < c; i += 256) {
        uint2 r = buf[i];
        int dl = r.x >> 17;
        unsigned pos = atomicAdd(&cur[dl], 1u);
        uint2 o; o.x = r.x & 0x1FFFFu; o.y = r.y;
        recs[base + pos] = o;
    }
}

// ---------------------------------------------------------------------------
// agg helper: wave aggregates 8 nodes into the LDS z-tile (8-edge
// unconditional-clamped ILP, R9 pattern).
// ---------------------------------------------------------------------------
__device__ __forceinline__ void agg_to_lds(const f16* __restrict__ Xi,
                                           const float* __restrict__ dinv,
                                           const int* __restrict__ nstart,
                                           const int* __restrict__ ncnt,
                                           const uint2* __restrict__ recs,
                                           f16* __restrict__ Xs,
                                           int wave, int lane, int nb) {
    int g = lane >> 3, l7 = lane & 7;
    for (int nn = 0; nn < 8; ++nn) {
        int node = nb + nn;
        int st = nstart[node], c = ncnt[node];
        float acc[16];
        #pragma unroll
        for (int k = 0; k < 16; ++k) acc[k] = 0.f;
        for (int j = 0; j < c; j += 8) {
            int jj = j + g;
            int idx = st + (jj < c ? jj : c - 1);     // always valid
            uint2 r = recs[idx];                      // unconditional
            float cf = dinv[r.x] * __uint_as_float(r.y);
            float cc = (jj < c) ? cf : 0.f;
            const f16* rp = Xi + (size_t)r.x * 128 + l7 * 16;
            h8 h0 = *(const h8*)rp;
            h8 h1 = *(const h8*)(rp + 8);
            #pragma unroll
            for (int k = 0; k < 8; ++k) acc[k]     += cc * (float)h0[k];
            #pragma unroll
            for (int k = 0; k < 8; ++k) acc[k + 8] += cc * (float)h1[k];
        }
        #pragma unroll
        for (int k = 0; k < 16; ++k) {
            acc[k] += __shfl_xor(acc[k], 8);
            acc[k] += __shfl_xor(acc[k], 16);
            acc[k] += __shfl_xor(acc[k], 32);
        }
        if (g == 0) {
            float dn = dinv[node], d2 = dn * dn;
            const f16* sp = Xi + (size_t)node * 128 + l7 * 16;
            h8 s0 = *(const h8*)sp;
            h8 s1 = *(const h8*)(sp + 8);
            h8 o0, o1;
            #pragma unroll
            for (int k = 0; k < 8; ++k) o0[k] = (f16)(dn * acc[k]     + d2 * (float)s0[k]);
            #pragma unroll
            for (int k = 0; k < 8; ++k) o1[k] = (f16)(dn * acc[k + 8] + d2 * (float)s1[k]);
            f16* zp = Xs + (wave * 8 + nn) * GP + l7 * 16;
            *(h8*)zp = o0;
            *(h8*)(zp + 8) = o1;
        }
    }
}

// ---------------------------------------------------------------------------
// fusedL0: 256 thr / 32 nodes. Agg -> LDS z (9 KB only: W stays in GLOBAL,
// 32 KB WT is L1-resident — R11's 34 KB W LDS halved occupancy, 49.6%).
// Then 32x128 @ 128x128 MFMA, B-frags loaded from global; leaky(+b) -> Xo.
// ---------------------------------------------------------------------------
__global__ __launch_bounds__(256, 8) void fusedL0(const f16* __restrict__ Xi,
                                                  const float* __restrict__ dinv,
                                                  const int* __restrict__ nstart,
                                                  const int* __restrict__ ncnt,
                                                  const uint2* __restrict__ recs,
                                                  const f16* __restrict__ WT,
                                                  const float* __restrict__ bias,
                                                  f16* __restrict__ Xo) {
    __shared__ f16 Xs[32 * GP];                       // 8.5 KB
    int t = threadIdx.x;
    int wave = t >> 6, lane = t & 63;
    agg_to_lds(Xi, dinv, nstart, ncnt, recs, Xs, wave, lane,
               blockIdx.x * 32 + wave * 8);
    __syncthreads();

    int quad = lane >> 4, l15 = lane & 15;
    int mtile = wave & 1, nh = wave >> 1;             // 2 m-tiles x 2 n-halves
    f4 a4[4]; f4 zero = {0.f, 0.f, 0.f, 0.f};
    #pragma unroll
    for (int i = 0; i < 4; ++i) a4[i] = zero;
    #pragma unroll
    for (int kk = 0; kk < 128; kk += 32) {
        h8 a = *(h8*)(Xs + (mtile * 16 + l15) * GP + kk + quad * 8);
        #pragma unroll
        for (int nt4 = 0; nt4 < 4; ++nt4) {
            int nt = nh * 4 + nt4;
            h8 b = *(const h8*)(WT + (nt * 16 + l15) * 128 + kk + quad * 8);
            a4[nt4] = __builtin_amdgcn_mfma_f32_16x16x32_f16(a, b, a4[nt4], 0, 0, 0);
        }
    }
    size_t rbase = (size_t)blockIdx.x * 32;
    #pragma unroll
    for (int nt4 = 0; nt4 < 4; ++nt4) {
        int col = (nh * 4 + nt4) * 16 + l15;
        float bb = bias[col];
        #pragma unroll
        for (int r = 0; r < 4; ++r) {
            size_t row = rbase + mtile * 16 + quad * 4 + r;
            float v = a4[nt4][r] + bb;
            v = v > 0.f ? v : NEG_SLOPE * v;
            Xo[row * 128 + col] = (f16)v;
        }
    }
}

// ---------------------------------------------------------------------------
// fusedL1: as fusedL0 + 128->20 GEMM in the epilogue: x2 -> LDS (z reuse),
// W2T (32x128, padded) B-frags from global, 4 MFMAs -> y (stride-32).
// x2 never touches HBM.
// ---------------------------------------------------------------------------
__global__ __launch_bounds__(256, 8) void fusedL1(const f16* __restrict__ Xi,
                                                  const float* __restrict__ dinv,
                                                  const int* __restrict__ nstart,
                                                  const int* __restrict__ ncnt,
                                                  const uint2* __restrict__ recs,
                                                  const f16* __restrict__ WT,
                                                  const float* __restrict__ bias,
                                                  const f16* __restrict__ W2T,
                                                  f16* __restrict__ Y) {
    __shared__ f16 Xs[32 * GP];
    int t = threadIdx.x;
    int wave = t >> 6, lane = t & 63;
    agg_to_lds(Xi, dinv, nstart, ncnt, recs, Xs, wave, lane,
               blockIdx.x * 32 + wave * 8);
    __syncthreads();

    int quad = lane >> 4, l15 = lane & 15;
    int mtile = wave & 1, nh = wave >> 1;
    f4 a4[4]; f4 zero = {0.f, 0.f, 0.f, 0.f};
    #pragma unroll
    for (int i = 0; i < 4; ++i) a4[i] = zero;
    #pragma unroll
    for (int kk = 0; kk < 128; kk += 32) {
        h8 a = *(h8*)(Xs + (mtile * 16 + l15) * GP + kk + quad * 8);
        #pragma unroll
        for (int nt4 = 0; nt4 < 4; ++nt4) {
            int nt = nh * 4 + nt4;
            h8 b = *(const h8*)(WT + (nt * 16 + l15) * 128 + kk + quad * 8);
            a4[nt4] = __builtin_amdgcn_mfma_f32_16x16x32_f16(a, b, a4[nt4], 0, 0, 0);
        }
    }
    __syncthreads();                                  // z reads done
    #pragma unroll
    for (int nt4 = 0; nt4 < 4; ++nt4) {               // x2 = leaky(acc+b) -> LDS
        int col = (nh * 4 + nt4) * 16 + l15;
        float bb = bias[col];
        #pragma unroll
        for (int r = 0; r < 4; ++r) {
            float v = a4[nt4][r] + bb;
            v = v > 0.f ? v : NEG_SLOPE * v;
            Xs[(mtile * 16 + quad * 4 + r) * GP + col] = (f16)v;
        }
    }
    __syncthreads();
    int mt2 = wave & 1, nt2 = wave >> 1;              // 32x32 y tile, 4 waves
    f4 ya = zero;
    #pragma unroll
    for (int kk = 0; kk < 128; kk += 32) {
        h8 a = *(h8*)(Xs + (mt2 * 16 + l15) * GP + kk + quad * 8);
        h8 b = *(const h8*)(W2T + (nt2 * 16 + l15) * 128 + kk + quad * 8);
        ya = __builtin_amdgcn_mfma_f32_16x16x32_f16(a, b, ya, 0, 0, 0);
    }
    size_t rbase = (size_t)blockIdx.x * 32;
    #pragma unroll
    for (int r = 0; r < 4; ++r) {
        size_t row = rbase + mt2 * 16 + quad * 4 + r;
        Y[row * 32 + nt2 * 16 + l15] = (f16)ya[r];
    }
}

// ---------------------------------------------------------------------------
// agg20L: out = LSM( b2 + dn*sum(dinv[s]*ew*Y[s]) + dn^2*Y[n] ).  8-edge
// unconditional clamped loads; lane loads h4 of the padded 64B row;
// xor(8,16,32) combine; group-local log-softmax.
// ---------------------------------------------------------------------------
__global__ __launch_bounds__(256) void agg20L(const f16* __restrict__ Y,
                                              const float* __restrict__ dinv,
                                              const int* __restrict__ nstart,
                                              const int* __restrict__ ncnt,
                                              const uint2* __restrict__ recs,
                                              const float* __restrict__ b2,
                                              float* __restrict__ out) {
    int wave = threadIdx.x >> 6, lane = threadIdx.x & 63;
    int g = lane >> 3, l7 = lane & 7;
    int node = blockIdx.x * 4 + wave;
    int st = nstart[node], c = ncnt[node];
    float acc[4];
    #pragma unroll
    for (int k = 0; k < 4; ++k) acc[k] = 0.f;

    #pragma unroll 2
    for (int j = 0; j < c; j += 8) {
        int jj = j + g;
        int idx = st + (jj < c ? jj : c - 1);
        uint2 r = recs[idx];
        float cf = dinv[r.x] * __uint_as_float(r.y);
        float cc = (jj < c) ? cf : 0.f;
        h4 hh = *(const h4*)(Y + (size_t)r.x * 32 + l7 * 4);
        #pragma unroll
        for (int k = 0; k < 4; ++k) acc[k] += cc * (float)hh[k];
    }
    #pragma unroll
    for (int k = 0; k < 4; ++k) {
        acc[k] += __shfl_xor(acc[k], 8);
        acc[k] += __shfl_xor(acc[k], 16);
        acc[k] += __shfl_xor(acc[k], 32);
    }
    float dn = dinv[node], d2 = dn * dn;
    h4 hz = *(const h4*)(Y + (size_t)node * 32 + l7 * 4);
    bool live = (l7 < 5);                             // 5 lanes x 4 = 20 classes
    float tv[4];
    float mx = -INFINITY;
    #pragma unroll
    for (int k = 0; k < 4; ++k) {
        tv[k] = live ? (b2[l7 * 4 + k] + dn * acc[k] + d2 * (float)hz[k]) : -INFINITY;
        mx = fmaxf(mx, tv[k]);
    }
    #pragma unroll
    for (int off = 1; off <= 4; off <<= 1) mx = fmaxf(mx, __shfl_xor(mx, off));
    float ex = 0.f;
    if (live) {
        #pragma unroll
        for (int k = 0; k < 4; ++k) ex += expf(tv[k] - mx);
    }
    #pragma unroll
    for (int off = 1; off <= 4; off <<= 1) ex += __shfl_xor(ex, off);
    float ls = logf(ex);
    if (g == 0 && live) {
        float4 o;
        o.x = tv[0] - mx - ls; o.y = tv[1] - mx - ls;
        o.z = tv[2] - mx - ls; o.w = tv[3] - mx - ls;
        *(float4*)(out + (size_t)node * CDIM + l7 * 4) = o;
    }
}

// ---------------------------------------------------------------------------
extern "C" void kernel_launch(void* const* d_in, const int* in_sizes, int n_in,
                              void* d_out, int out_size, void* d_ws, size_t ws_size,
                              hipStream_t stream) {
    (void)in_sizes; (void)n_in; (void)out_size; (void)ws_size;
    const int*   node_ids = (const int*)d_in[0];
    const int*   e_src    = (const int*)d_in[1];
    const int*   e_dst    = e_src + N_EDGES;
    const float* edge_w   = (const float*)d_in[2];
    const float* emb      = (const float*)d_in[3];
    const float* W0       = (const float*)d_in[4];
    const float* b0       = (const float*)d_in[5];
    const float* W1       = (const float*)d_in[6];
    const float* b1       = (const float*)d_in[7];
    const float* W2       = (const float*)d_in[8];
    const float* b2       = (const float*)d_in[9];
    float* out = (float*)d_out;

    char* w = (char*)d_ws;
    size_t off = 0;
    auto alloc = [&](size_t bytes) {
        void* p = w + off;
        off = (off + bytes + 255) & ~(size_t)255;
        return p;
    };
    f16*   xA     = (f16*)alloc((size_t)N_NODES * FDIM * 2);     // 25.6 MB
    f16*   xB     = (f16*)alloc((size_t)N_NODES * FDIM * 2);     // 25.6 MB
    f16*   ybuf   = (f16*)alloc((size_t)N_NODES * 32 * 2);       // 6.4 MB
    int*   histG  = (int*)alloc((size_t)NB * NPART * 4);         // 800 KB
    int*   pstart = (int*)alloc((size_t)(NPART + 1) * 4);
    int*   nstart = (int*)alloc((size_t)N_NODES * 4);
    int*   ncnt   = (int*)alloc((size_t)N_NODES * 4);
    float* dinv   = (float*)alloc((size_t)N_NODES * 4);
    f16*   W0T    = (f16*)alloc(16384 * 2);
    f16*   W1T    = (f16*)alloc(16384 * 2);
    f16*   W2T    = (f16*)alloc(32 * 128 * 2);
    uint2* recs   = (uint2*)alloc((size_t)N_EDGES * 8);          // 12.8 MB

    k1_build<<<NB + GATHER_BLOCKS + 128 + 16, 256, 0, stream>>>(
        node_ids, emb, xA, e_dst, histG, W0, W1, W2, W0T, W1T, W2T);
    k2a_scan<<<1, 1024, 0, stream>>>(histG, pstart);
    k2b_seed<<<(NPART + 3) / 4, 256, 0, stream>>>(histG, pstart);
    k3_scatter<<<NB, 256, 0, stream>>>(e_src, e_dst, edge_w, histG, recs);
    k4_repack<<<NPART, 256, 0, stream>>>(recs, pstart, nstart, ncnt, dinv);

    int fblocks = N_NODES / 32;                      // 3125 exact
    // layer 0:  x1 = leaky((A.x0) W0 + b0)          (agg+GEMM fused)
    fusedL0<<<fblocks, 256, 0, stream>>>(xA, dinv, nstart, ncnt, recs, W0T, b0, xB);
    // layer 1 + 128->20:  y = leaky((A.x1) W1 + b1) W2   (x2 never hits HBM)
    fusedL1<<<fblocks, 256, 0, stream>>>(xB, dinv, nstart, ncnt, recs, W1T, b1, W2T, ybuf);
    // out = LSM(b2 + A.y)
    agg20L<<<N_NODES / 4, 256, 0, stream>>>(ybuf, dinv, nstart, ncnt, recs, b2, out);
}

// Round 13
// 431.565 us; speedup vs baseline: 1.0638x; 1.0140x over previous
//
#include <hip/hip_runtime.h>
#include <math.h>

typedef _Float16 f16;
typedef _Float16 h8  __attribute__((ext_vector_type(8)));
typedef _Float16 h4  __attribute__((ext_vector_type(4)));
typedef float    f4  __attribute__((ext_vector_type(4)));

#define N_NODES 100000
#define N_EDGES 1600000
#define FDIM    128
#define CDIM    20
#define NEG_SLOPE 0.01f

#define NPART 782                    // partitions of 128 dst nodes
#define PCAP  2560                   // static region per partition (mean 2046, +11 sigma)
#define NB    256                    // histogram/scatter blocks
#define EPB   (N_EDGES / NB)         // 6250 edges per block
#define PBUF  2944                   // repack LDS capacity
#define GATHER_BLOCKS (N_NODES * 32 / 256)   // 12500
#define GP    136                    // LDS pitch in halves

// ---------------------------------------------------------------------------
// K1 (fused): [0,NB) per-block dst-partition histograms (LDS atomics);
// [NB, NB+GATHER) emb-row gather fp32->fp16 into xA; then 128 blocks
// transpose W0/W1 to fp16 [n][k]; last 16 blocks build W2T (32x128, padded).
// ---------------------------------------------------------------------------
__global__ __launch_bounds__(256) void k1_build(const int* __restrict__ ids,
                                                const float* __restrict__ emb,
                                                f16* __restrict__ X,
                                                const int* __restrict__ dst,
                                                int* __restrict__ histG,
                                                const float* __restrict__ W0,
                                                const float* __restrict__ W1,
                                                const float* __restrict__ W2,
                                                f16* __restrict__ W0T,
                                                f16* __restrict__ W1T,
                                                f16* __restrict__ W2T) {
    int b = blockIdx.x, t = threadIdx.x;
    if (b < NB) {
        __shared__ unsigned lh[NPART];
        for (int i = t; i < NPART; i += 256) lh[i] = 0;
        __syncthreads();
        int e0 = b * EPB;
        for (int i = t; i < EPB; i += 256)
            atomicAdd(&lh[dst[e0 + i] >> 7], 1u);
        __syncthreads();
        for (int i = t; i < NPART; i += 256) histG[b * NPART + i] = (int)lh[i];
    } else if (b < NB + GATHER_BLOCKS) {
        int gid = (b - NB) * 256 + t;                 // N*32 exact
        int n = gid >> 5, qq = gid & 31;
        int v = ids[n];
        float4 vv = ((const float4*)emb)[(size_t)v * 32 + qq];
        h4 o; o[0] = (f16)vv.x; o[1] = (f16)vv.y; o[2] = (f16)vv.z; o[3] = (f16)vv.w;
        ((h4*)X)[(size_t)n * 32 + qq] = o;
    } else if (b < NB + GATHER_BLOCKS + 128) {
        int o = (b - NB - GATHER_BLOCKS) * 256 + t;   // 32768 total
        const float* W = (o < 16384) ? W0 : W1;
        f16* T = (o < 16384) ? W0T : W1T;
        int o2 = o & 16383;
        int n = o2 >> 7, k = o2 & 127;
        T[o2] = (f16)W[k * 128 + n];
    } else {
        int o = (b - NB - GATHER_BLOCKS - 128) * 256 + t;   // 4096 total
        int cc = o >> 7, k = o & 127;
        W2T[o] = (cc < CDIM) ? (f16)W2[k * CDIM + cc] : (f16)0.f;
    }
}

// ---------------------------------------------------------------------------
// K2: one wave per partition. Static region base = p*PCAP (NO global scan —
// R12's single-block k2a_scan ran 200K strided loads on 1/256 of the GPU).
// Wave-scan the 256 per-block counts -> seed offsets; write ptot[p].
// ---------------------------------------------------------------------------
__global__ __launch_bounds__(256) void k2_seed(int* __restrict__ histG,
                                               int* __restrict__ ptot) {
    int w = blockIdx.x * 4 + (threadIdx.x >> 6);
    if (w >= NPART) return;
    int lane = threadIdx.x & 63;
    int base = w * PCAP;
    int v[4], pre[4], s = 0;
    #pragma unroll
    for (int i = 0; i < 4; ++i) v[i] = histG[(lane * 4 + i) * NPART + w];
    #pragma unroll
    for (int i = 0; i < 4; ++i) { pre[i] = s; s += v[i]; }
    int ss = s;
    #pragma unroll
    for (int off = 1; off < 64; off <<= 1) {
        int u = __shfl_up(ss, off);
        if (lane >= off) ss += u;
    }
    if (lane == 63) ptot[w] = ss;                     // partition total
    int wexcl = ss - s;
    #pragma unroll
    for (int i = 0; i < 4; ++i)
        histG[(lane * 4 + i) * NPART + w] = base + wexcl + pre[i];
}

// ---------------------------------------------------------------------------
// K3: deterministic scatter via LDS cursors seeded from exact offsets.
//   rec = ((dl<<17)|src, ew_f32); region-bound guard vs PCAP overflow.
// ---------------------------------------------------------------------------
__global__ __launch_bounds__(256) void k3_scatter(const int* __restrict__ src,
                                                  const int* __restrict__ dst,
                                                  const float* __restrict__ ew,
                                                  const int* __restrict__ histG,
                                                  uint2* __restrict__ recs) {
    __shared__ unsigned cur[NPART];
    int b = blockIdx.x, t = threadIdx.x;
    for (int i = t; i < NPART; i += 256) cur[i] = (unsigned)histG[b * NPART + i];
    __syncthreads();
    int e0 = b * EPB;
    for (int i = t; i < EPB; i += 256) {
        int e = e0 + i;
        int s = src[e], d = dst[e];
        int p = d >> 7, dl = d & 127;
        unsigned pos = atomicAdd(&cur[p], 1u);        // LDS atomic only
        if (pos < (unsigned)((p + 1) * PCAP)) {       // ~1e-20 overflow guard
            uint2 r; r.x = ((unsigned)dl << 17) | (unsigned)s; r.y = __float_as_uint(ew[e]);
            recs[pos] = r;
        }
    }
}

// ---------------------------------------------------------------------------
// K4: per-partition repack: sort records by dst_local in LDS, emit
// nstart/ncnt, weighted degree -> dinv. Strips dl from rec.x.
// ---------------------------------------------------------------------------
__global__ __launch_bounds__(256) void k4_repack(uint2* __restrict__ recs,
                                                 const int* __restrict__ ptot,
                                                 int* __restrict__ nstart,
                                                 int* __restrict__ ncnt,
                                                 float* __restrict__ dinv) {
    __shared__ uint2    buf[PBUF];                    // 23.5 KB
    __shared__ float    wsum[128];
    __shared__ unsigned hcnt[128], pref[128], cur[128];
    int p = blockIdx.x, t = threadIdx.x;
    if (t < 128) { hcnt[t] = 0; wsum[t] = 0.f; }
    __syncthreads();
    int base = p * PCAP;
    int c = ptot[p];
    if (c > PCAP) c = PCAP;
    for (int i = t; i < c; i += 256) {
        uint2 r = recs[base + i];
        buf[i] = r;
        int dl = r.x >> 17;
        atomicAdd(&hcnt[dl], 1u);
        atomicAdd(&wsum[dl], __uint_as_float(r.y));
    }
    __syncthreads();
    if (t == 0) {
        unsigned s = 0;
        for (int k = 0; k < 128; ++k) { pref[k] = s; s += hcnt[k]; }
    }
    __syncthreads();
    if (t < 128) {
        cur[t] = pref[t];
        int g = p * 128 + t;
        if (g < N_NODES) {
            nstart[g] = base + (int)pref[t];
            ncnt[g]   = (int)hcnt[t];
            dinv[g]   = rsqrtf(wsum[t] + 1.0f);
        }
    }
    __syncthreads();
    for (int i = t; i < c; i += 256) {
        uint2 r = buf[i];
        int dl = r.x >> 17;
        unsigned pos = atomicAdd(&cur[dl], 1u);
        uint2 o; o.x = r.x & 0x1FFFFu; o.y = r.y;
        recs[base + pos] = o;
    }
}

// ---------------------------------------------------------------------------
// agg helper: wave aggregates 8 nodes into the LDS z-tile. 8-edge batches,
// UNCONDITIONAL clamped loads + unroll 2 (R9/R12 lesson: the unroll is what
// makes the compiler software-pipeline gathers across batches — dropping it
// cost VALUBusy 58->34%).
// ---------------------------------------------------------------------------
__device__ __forceinline__ void agg_to_lds(const f16* __restrict__ Xi,
                                           const float* __restrict__ dinv,
                                           const int* __restrict__ nstart,
                                           const int* __restrict__ ncnt,
                                           const uint2* __restrict__ recs,
                                           f16* __restrict__ Xs,
                                           int wave, int lane, int nb) {
    int g = lane >> 3, l7 = lane & 7;
    for (int nn = 0; nn < 8; ++nn) {
        int node = nb + nn;
        int st = nstart[node], c = ncnt[node];
        float acc[16];
        #pragma unroll
        for (int k = 0; k < 16; ++k) acc[k] = 0.f;
        #pragma unroll 2
        for (int j = 0; j < c; j += 8) {
            int jj = j + g;
            int idx = st + (jj < c ? jj : c - 1);     // always valid
            uint2 r = recs[idx];                      // unconditional
            float cf = dinv[r.x] * __uint_as_float(r.y);
            float cc = (jj < c) ? cf : 0.f;
            const f16* rp = Xi + (size_t)r.x * 128 + l7 * 16;
            h8 h0 = *(const h8*)rp;
            h8 h1 = *(const h8*)(rp + 8);
            #pragma unroll
            for (int k = 0; k < 8; ++k) acc[k]     += cc * (float)h0[k];
            #pragma unroll
            for (int k = 0; k < 8; ++k) acc[k + 8] += cc * (float)h1[k];
        }
        #pragma unroll
        for (int k = 0; k < 16; ++k) {
            acc[k] += __shfl_xor(acc[k], 8);
            acc[k] += __shfl_xor(acc[k], 16);
            acc[k] += __shfl_xor(acc[k], 32);
        }
        if (g == 0) {
            float dn = dinv[node], d2 = dn * dn;
            const f16* sp = Xi + (size_t)node * 128 + l7 * 16;
            h8 s0 = *(const h8*)sp;
            h8 s1 = *(const h8*)(sp + 8);
            h8 o0, o1;
            #pragma unroll
            for (int k = 0; k < 8; ++k) o0[k] = (f16)(dn * acc[k]     + d2 * (float)s0[k]);
            #pragma unroll
            for (int k = 0; k < 8; ++k) o1[k] = (f16)(dn * acc[k + 8] + d2 * (float)s1[k]);
            f16* zp = Xs + (wave * 8 + nn) * GP + l7 * 16;
            *(h8*)zp = o0;
            *(h8*)(zp + 8) = o1;
        }
    }
}

// ---------------------------------------------------------------------------
// fusedL0: 256 thr / 32 nodes. Agg -> LDS z (8.5 KB; W stays in global,
// L1-resident). Then 32x128 @ 128x128 MFMA; leaky(+b) -> Xo.
// ---------------------------------------------------------------------------
__global__ __launch_bounds__(256, 8) void fusedL0(const f16* __restrict__ Xi,
                                                  const float* __restrict__ dinv,
                                                  const int* __restrict__ nstart,
                                                  const int* __restrict__ ncnt,
                                                  const uint2* __restrict__ recs,
                                                  const f16* __restrict__ WT,
                                                  const float* __restrict__ bias,
                                                  f16* __restrict__ Xo) {
    __shared__ f16 Xs[32 * GP];                       // 8.5 KB
    int t = threadIdx.x;
    int wave = t >> 6, lane = t & 63;
    agg_to_lds(Xi, dinv, nstart, ncnt, recs, Xs, wave, lane,
               blockIdx.x * 32 + wave * 8);
    __syncthreads();

    int quad = lane >> 4, l15 = lane & 15;
    int mtile = wave & 1, nh = wave >> 1;             // 2 m-tiles x 2 n-halves
    f4 a4[4]; f4 zero = {0.f, 0.f, 0.f, 0.f};
    #pragma unroll
    for (int i = 0; i < 4; ++i) a4[i] = zero;
    #pragma unroll
    for (int kk = 0; kk < 128; kk += 32) {
        h8 a = *(h8*)(Xs + (mtile * 16 + l15) * GP + kk + quad * 8);
        #pragma unroll
        for (int nt4 = 0; nt4 < 4; ++nt4) {
            int nt = nh * 4 + nt4;
            h8 b = *(const h8*)(WT + (nt * 16 + l15) * 128 + kk + quad * 8);
            a4[nt4] = __builtin_amdgcn_mfma_f32_16x16x32_f16(a, b, a4[nt4], 0, 0, 0);
        }
    }
    size_t rbase = (size_t)blockIdx.x * 32;
    #pragma unroll
    for (int nt4 = 0; nt4 < 4; ++nt4) {
        int col = (nh * 4 + nt4) * 16 + l15;
        float bb = bias[col];
        #pragma unroll
        for (int r = 0; r < 4; ++r) {
            size_t row = rbase + mtile * 16 + quad * 4 + r;
            float v = a4[nt4][r] + bb;
            v = v > 0.f ? v : NEG_SLOPE * v;
            Xo[row * 128 + col] = (f16)v;
        }
    }
}

// ---------------------------------------------------------------------------
// fusedL1: as fusedL0 + 128->20 GEMM in the epilogue (x2 via LDS, W2T from
// global, y stride-32). x2 never touches HBM.
// ---------------------------------------------------------------------------
__global__ __launch_bounds__(256, 8) void fusedL1(const f16* __restrict__ Xi,
                                                  const float* __restrict__ dinv,
                                                  const int* __restrict__ nstart,
                                                  const int* __restrict__ ncnt,
                                                  const uint2* __restrict__ recs,
                                                  const f16* __restrict__ WT,
                                                  const float* __restrict__ bias,
                                                  const f16* __restrict__ W2T,
                                                  f16* __restrict__ Y) {
    __shared__ f16 Xs[32 * GP];
    int t = threadIdx.x;
    int wave = t >> 6, lane = t & 63;
    agg_to_lds(Xi, dinv, nstart, ncnt, recs, Xs, wave, lane,
               blockIdx.x * 32 + wave * 8);
    __syncthreads();

    int quad = lane >> 4, l15 = lane & 15;
    int mtile = wave & 1, nh = wave >> 1;
    f4 a4[4]; f4 zero = {0.f, 0.f, 0.f, 0.f};
    #pragma unroll
    for (int i = 0; i < 4; ++i) a4[i] = zero;
    #pragma unroll
    for (int kk = 0; kk < 128; kk += 32) {
        h8 a = *(h8*)(Xs + (mtile * 16 + l15) * GP + kk + quad * 8);
        #pragma unroll
        for (int nt4 = 0; nt4 < 4; ++nt4) {
            int nt = nh * 4 + nt4;
            h8 b = *(const h8*)(WT + (nt * 16 + l15) * 128 + kk + quad * 8);
            a4[nt4] = __builtin_amdgcn_mfma_f32_16x16x32_f16(a, b, a4[nt4], 0, 0, 0);
        }
    }
    __syncthreads();                                  // z reads done
    #pragma unroll
    for (int nt4 = 0; nt4 < 4; ++nt4) {               // x2 = leaky(acc+b) -> LDS
        int col = (nh * 4 + nt4) * 16 + l15;
        float bb = bias[col];
        #pragma unroll
        for (int r = 0; r < 4; ++r) {
            float v = a4[nt4][r] + bb;
            v = v > 0.f ? v : NEG_SLOPE * v;
            Xs[(mtile * 16 + quad * 4 + r) * GP + col] = (f16)v;
        }
    }
    __syncthreads();
    int mt2 = wave & 1, nt2 = wave >> 1;              // 32x32 y tile, 4 waves
    f4 ya = zero;
    #pragma unroll
    for (int kk = 0; kk < 128; kk += 32) {
        h8 a = *(h8*)(Xs + (mt2 * 16 + l15) * GP + kk + quad * 8);
        h8 b = *(const h8*)(W2T + (nt2 * 16 + l15) * 128 + kk + quad * 8);
        ya = __builtin_amdgcn_mfma_f32_16x16x32_f16(a, b, ya, 0, 0, 0);
    }
    size_t rbase = (size_t)blockIdx.x * 32;
    #pragma unroll
    for (int r = 0; r < 4; ++r) {
        size_t row = rbase + mt2 * 16 + quad * 4 + r;
        Y[row * 32 + nt2 * 16 + l15] = (f16)ya[r];
    }
}

// ---------------------------------------------------------------------------
// agg20L: out = LSM( b2 + dn*sum(dinv[s]*ew*Y[s]) + dn^2*Y[n] ).
// ---------------------------------------------------------------------------
__global__ __launch_bounds__(256) void agg20L(const f16* __restrict__ Y,
                                              const float* __restrict__ dinv,
                                              const int* __restrict__ nstart,
                                              const int* __restrict__ ncnt,
                                              const uint2* __restrict__ recs,
                                              const float* __restrict__ b2,
                                              float* __restrict__ out) {
    int wave = threadIdx.x >> 6, lane = threadIdx.x & 63;
    int g = lane >> 3, l7 = lane & 7;
    int node = blockIdx.x * 4 + wave;
    int st = nstart[node], c = ncnt[node];
    float acc[4];
    #pragma unroll
    for (int k = 0; k < 4; ++k) acc[k] = 0.f;

    #pragma unroll 2
    for (int j = 0; j < c; j += 8) {
        int jj = j + g;
        int idx = st + (jj < c ? jj : c - 1);
        uint2 r = recs[idx];
        float cf = dinv[r.x] * __uint_as_float(r.y);
        float cc = (jj < c) ? cf : 0.f;
        h4 hh = *(const h4*)(Y + (size_t)r.x * 32 + l7 * 4);
        #pragma unroll
        for (int k = 0; k < 4; ++k) acc[k] += cc * (float)hh[k];
    }
    #pragma unroll
    for (int k = 0; k < 4; ++k) {
        acc[k] += __shfl_xor(acc[k], 8);
        acc[k] += __shfl_xor(acc[k], 16);
        acc[k] += __shfl_xor(acc[k], 32);
    }
    float dn = dinv[node], d2 = dn * dn;
    h4 hz = *(const h4*)(Y + (size_t)node * 32 + l7 * 4);
    bool live = (l7 < 5);                             // 5 lanes x 4 = 20 classes
    float tv[4];
    float mx = -INFINITY;
    #pragma unroll
    for (int k = 0; k < 4; ++k) {
        tv[k] = live ? (b2[l7 * 4 + k] + dn * acc[k] + d2 * (float)hz[k]) : -INFINITY;
        mx = fmaxf(mx, tv[k]);
    }
    #pragma unroll
    for (int off = 1; off <= 4; off <<= 1) mx = fmaxf(mx, __shfl_xor(mx, off));
    float ex = 0.f;
    if (live) {
        #pragma unroll
        for (int k = 0; k < 4; ++k) ex += expf(tv[k] - mx);
    }
    #pragma unroll
    for (int off = 1; off <= 4; off <<= 1) ex += __shfl_xor(ex, off);
    float ls = logf(ex);
    if (g == 0 && live) {
        float4 o;
        o.x = tv[0] - mx - ls; o.y = tv[1] - mx - ls;
        o.z = tv[2] - mx - ls; o.w = tv[3] - mx - ls;
        *(float4*)(out + (size_t)node * CDIM + l7 * 4) = o;
    }
}

// ---------------------------------------------------------------------------
extern "C" void kernel_launch(void* const* d_in, const int* in_sizes, int n_in,
                              void* d_out, int out_size, void* d_ws, size_t ws_size,
                              hipStream_t stream) {
    (void)in_sizes; (void)n_in; (void)out_size; (void)ws_size;
    const int*   node_ids = (const int*)d_in[0];
    const int*   e_src    = (const int*)d_in[1];
    const int*   e_dst    = e_src + N_EDGES;
    const float* edge_w   = (const float*)d_in[2];
    const float* emb      = (const float*)d_in[3];
    const float* W0       = (const float*)d_in[4];
    const float* b0       = (const float*)d_in[5];
    const float* W1       = (const float*)d_in[6];
    const float* b1       = (const float*)d_in[7];
    const float* W2       = (const float*)d_in[8];
    const float* b2       = (const float*)d_in[9];
    float* out = (float*)d_out;

    char* w = (char*)d_ws;
    size_t off = 0;
    auto alloc = [&](size_t bytes) {
        void* p = w + off;
        off = (off + bytes + 255) & ~(size_t)255;
        return p;
    };
    f16*   xA     = (f16*)alloc((size_t)N_NODES * FDIM * 2);     // 25.6 MB
    f16*   xB     = (f16*)alloc((size_t)N_NODES * FDIM * 2);     // 25.6 MB
    f16*   ybuf   = (f16*)alloc((size_t)N_NODES * 32 * 2);       // 6.4 MB
    int*   histG  = (int*)alloc((size_t)NB * NPART * 4);         // 800 KB
    int*   ptot   = (int*)alloc((size_t)NPART * 4);
    int*   nstart = (int*)alloc((size_t)N_NODES * 4);
    int*   ncnt   = (int*)alloc((size_t)N_NODES * 4);
    float* dinv   = (float*)alloc((size_t)N_NODES * 4);
    f16*   W0T    = (f16*)alloc(16384 * 2);
    f16*   W1T    = (f16*)alloc(16384 * 2);
    f16*   W2T    = (f16*)alloc(32 * 128 * 2);
    uint2* recs   = (uint2*)alloc((size_t)NPART * PCAP * 8);     // 16.0 MB

    k1_build<<<NB + GATHER_BLOCKS + 128 + 16, 256, 0, stream>>>(
        node_ids, emb, xA, e_dst, histG, W0, W1, W2, W0T, W1T, W2T);
    k2_seed<<<(NPART + 3) / 4, 256, 0, stream>>>(histG, ptot);
    k3_scatter<<<NB, 256, 0, stream>>>(e_src, e_dst, edge_w, histG, recs);
    k4_repack<<<NPART, 256, 0, stream>>>(recs, ptot, nstart, ncnt, dinv);

    int fblocks = N_NODES / 32;                      // 3125 exact
    // layer 0:  x1 = leaky((A.x0) W0 + b0)          (agg+GEMM fused)
    fusedL0<<<fblocks, 256, 0, stream>>>(xA, dinv, nstart, ncnt, recs, W0T, b0, xB);
    // layer 1 + 128->20:  y = leaky((A.x1) W1 + b1) W2   (x2 never hits HBM)
    fusedL1<<<fblocks, 256, 0, stream>>>(xB, dinv, nstart, ncnt, recs, W1T, b1, W2T, ybuf);
    // out = LSM(b2 + A.y)
    agg20L<<<N_NODES / 4, 256, 0, stream>>>(ybuf, dinv, nstart, ncnt, recs, b2, out);
}